// Round 1
// baseline (72.530 us; speedup 1.0000x reference)
//
#include <hip/hip_runtime.h>
#include <math.h>

// PointOnSurfaceLoss: B=8, M=512, N=8192
//   keypoint: (B,3,M) fp32, pc: (B,3,N) fp32, sn: (B,3,N) fp32
//   out: (B,M,1,1) fp32 = (sn_sel . d_unit)^2 where sel = argmin_n ||kp - pc_n||
//
// Structure: 1 block of 256 threads per (b,m) keypoint. Each thread scans
// N/256/4 = 8 float4-vectorized chunks of the pc rows, tracking (min d2, idx)
// with first-occurrence tie-break. Wave64 shuffle reduce + LDS cross-wave
// reduce, thread 0 runs the epilogue.

#define PB 8
#define PM 512
#define PN 8192
#define PEPS 1e-7f

__device__ __forceinline__ void combine_min(float& d2, int& idx, float od2, int oidx) {
    if (od2 < d2 || (od2 == d2 && oidx < idx)) { d2 = od2; idx = oidx; }
}

__global__ __launch_bounds__(256) void posloss_kernel(
    const float* __restrict__ keypoint,  // B*3*M
    const float* __restrict__ pc,        // B*3*N
    const float* __restrict__ sn,        // B*3*N
    float* __restrict__ out)             // B*M
{
    const int bm  = blockIdx.x;          // 0 .. B*M-1
    const int b   = bm >> 9;             // / 512
    const int m   = bm & 511;
    const int tid = threadIdx.x;

    const float* kp = keypoint + b * 3 * PM;
    const float kx = kp[0 * PM + m];
    const float ky = kp[1 * PM + m];
    const float kz = kp[2 * PM + m];

    const float* pcx = pc + b * 3 * PN;
    const float* pcy = pcx + PN;
    const float* pcz = pcy + PN;

    float best = 3.4e38f;
    int   bidx = 0;

    // float4-vectorized scan: thread t handles points [4t .. 4t+3], stride 1024
    const float4* px4 = (const float4*)pcx;
    const float4* py4 = (const float4*)pcy;
    const float4* pz4 = (const float4*)pcz;
    #pragma unroll
    for (int it = 0; it < PN / (256 * 4); ++it) {
        const int v = it * 256 + tid;           // float4 index
        const int n0 = v * 4;                   // point index of .x
        float4 x4 = px4[v];
        float4 y4 = py4[v];
        float4 z4 = pz4[v];
        float dx, dy, dz, d2;
        dx = kx - x4.x; dy = ky - y4.x; dz = kz - z4.x;
        d2 = dx * dx + dy * dy + dz * dz;
        if (d2 < best) { best = d2; bidx = n0 + 0; }
        dx = kx - x4.y; dy = ky - y4.y; dz = kz - z4.y;
        d2 = dx * dx + dy * dy + dz * dz;
        if (d2 < best) { best = d2; bidx = n0 + 1; }
        dx = kx - x4.z; dy = ky - y4.z; dz = kz - z4.z;
        d2 = dx * dx + dy * dy + dz * dz;
        if (d2 < best) { best = d2; bidx = n0 + 2; }
        dx = kx - x4.w; dy = ky - y4.w; dz = kz - z4.w;
        d2 = dx * dx + dy * dy + dz * dz;
        if (d2 < best) { best = d2; bidx = n0 + 3; }
    }

    // Wave64 shuffle reduction (tie-break: smaller index wins)
    #pragma unroll
    for (int off = 32; off > 0; off >>= 1) {
        float od2  = __shfl_down(best, off);
        int   oidx = __shfl_down(bidx, off);
        combine_min(best, bidx, od2, oidx);
    }

    __shared__ float s_d2[4];
    __shared__ int   s_idx[4];
    const int wave = tid >> 6;
    const int lane = tid & 63;
    if (lane == 0) { s_d2[wave] = best; s_idx[wave] = bidx; }
    __syncthreads();

    if (tid == 0) {
        best = s_d2[0]; bidx = s_idx[0];
        #pragma unroll
        for (int w = 1; w < 4; ++w) combine_min(best, bidx, s_d2[w], s_idx[w]);

        const float px = pcx[bidx], py = pcy[bidx], pz = pcz[bidx];
        const float* snb = sn + b * 3 * PN;
        const float sx = snb[0 * PN + bidx];
        const float sy = snb[1 * PN + bidx];
        const float sz = snb[2 * PN + bidx];

        const float dx = kx - px, dy = ky - py, dz = kz - pz;
        const float dn = sqrtf(dx * dx + dy * dy + dz * dz);
        const float inv = 1.0f / (dn + PEPS);
        const float dot = sx * (dx * inv) + sy * (dy * inv) + sz * (dz * inv);
        out[bm] = dot * dot;
    }
}

extern "C" void kernel_launch(void* const* d_in, const int* in_sizes, int n_in,
                              void* d_out, int out_size, void* d_ws, size_t ws_size,
                              hipStream_t stream) {
    const float* keypoint = (const float*)d_in[0];  // B*3*M
    const float* pc       = (const float*)d_in[1];  // B*3*N
    const float* sn       = (const float*)d_in[2];  // B*3*N
    float* out            = (float*)d_out;          // B*M

    posloss_kernel<<<PB * PM, 256, 0, stream>>>(keypoint, pc, sn, out);
}

// Round 2
// 68.677 us; speedup vs baseline: 1.0561x; 1.0561x over previous
//
#include <hip/hip_runtime.h>
#include <math.h>

// PointOnSurfaceLoss: B=8, M=512, N=8192
//   keypoint: (B,3,M) fp32, pc: (B,3,N) fp32, sn: (B,3,N) fp32
//   out: (B,M,1,1) fp32 = (sn_sel . d_unit)^2, sel = argmin_n ||kp - pc_n||
//
// R1 structure: 1 block (256 threads) per KPB=4 keypoints. Each thread scans
// 32 points (8 float4 iters) and tests them against all 4 keypoints held in
// registers -> 4x fewer global loads than R0 (100 MB total L1 traffic),
// VALU-bound at ~302M lane-ops. Grid = 1024 blocks = 4 blocks/CU, 16 waves/CU.

#define PB 8
#define PM 512
#define PN 8192
#define KPB 4
#define PEPS 1e-7f

__device__ __forceinline__ void combine_min(float& d2, int& idx, float od2, int oidx) {
    if (od2 < d2 || (od2 == d2 && oidx < idx)) { d2 = od2; idx = oidx; }
}

__global__ __launch_bounds__(256) void posloss_kernel(
    const float* __restrict__ keypoint,  // B*3*M
    const float* __restrict__ pc,        // B*3*N
    const float* __restrict__ sn,        // B*3*N
    float* __restrict__ out)             // B*M
{
    const int blk = blockIdx.x;              // 0 .. B*M/KPB - 1
    const int b   = blk >> 7;                // 128 blocks per batch (512/4)
    const int m0  = (blk & 127) * KPB;
    const int tid = threadIdx.x;

    // wave-uniform keypoint coords (scalar loads)
    const float* kp = keypoint + b * 3 * PM;
    float kx[KPB], ky[KPB], kz[KPB];
    #pragma unroll
    for (int k = 0; k < KPB; ++k) {
        kx[k] = kp[0 * PM + m0 + k];
        ky[k] = kp[1 * PM + m0 + k];
        kz[k] = kp[2 * PM + m0 + k];
    }

    const float* pcx = pc + b * 3 * PN;
    const float* pcy = pcx + PN;
    const float* pcz = pcy + PN;

    float best[KPB];
    int   bidx[KPB];
    #pragma unroll
    for (int k = 0; k < KPB; ++k) { best[k] = 3.4e38f; bidx[k] = 0; }

    const float4* px4 = (const float4*)pcx;
    const float4* py4 = (const float4*)pcy;
    const float4* pz4 = (const float4*)pcz;

    #pragma unroll
    for (int it = 0; it < PN / (256 * 4); ++it) {   // 8 iterations
        const int v  = it * 256 + tid;              // float4 index
        const int n0 = v * 4;                       // point index of .x
        const float4 x4 = px4[v];
        const float4 y4 = py4[v];
        const float4 z4 = pz4[v];
        const float xs[4] = {x4.x, x4.y, x4.z, x4.w};
        const float ys[4] = {y4.x, y4.y, y4.z, y4.w};
        const float zs[4] = {z4.x, z4.y, z4.z, z4.w};
        #pragma unroll
        for (int j = 0; j < 4; ++j) {
            const float px = xs[j], py = ys[j], pz = zs[j];
            #pragma unroll
            for (int k = 0; k < KPB; ++k) {
                const float dx = kx[k] - px;
                const float dy = ky[k] - py;
                const float dz = kz[k] - pz;
                const float d2 = dx * dx + dy * dy + dz * dz;
                if (d2 < best[k]) { best[k] = d2; bidx[k] = n0 + j; }
            }
        }
    }

    // Wave64 shuffle reduction per keypoint (tie-break: smaller index wins)
    #pragma unroll
    for (int k = 0; k < KPB; ++k) {
        #pragma unroll
        for (int off = 32; off > 0; off >>= 1) {
            float od2  = __shfl_down(best[k], off);
            int   oidx = __shfl_down(bidx[k], off);
            combine_min(best[k], bidx[k], od2, oidx);
        }
    }

    __shared__ float s_d2[4][KPB];
    __shared__ int   s_idx[4][KPB];
    const int wave = tid >> 6;
    const int lane = tid & 63;
    if (lane == 0) {
        #pragma unroll
        for (int k = 0; k < KPB; ++k) { s_d2[wave][k] = best[k]; s_idx[wave][k] = bidx[k]; }
    }
    __syncthreads();

    if (tid < KPB) {
        const int k = tid;
        float bd = s_d2[0][k];
        int   bi = s_idx[0][k];
        #pragma unroll
        for (int w = 1; w < 4; ++w) combine_min(bd, bi, s_d2[w][k], s_idx[w][k]);

        const float px = pcx[bi], py = pcy[bi], pz = pcz[bi];
        const float* snb = sn + b * 3 * PN;
        const float sx = snb[0 * PN + bi];
        const float sy = snb[1 * PN + bi];
        const float sz = snb[2 * PN + bi];

        const float dx = kx[k] - px, dy = ky[k] - py, dz = kz[k] - pz;
        const float dn = sqrtf(dx * dx + dy * dy + dz * dz);
        const float inv = 1.0f / (dn + PEPS);
        const float dot = sx * (dx * inv) + sy * (dy * inv) + sz * (dz * inv);
        out[b * PM + m0 + k] = dot * dot;
    }
}

extern "C" void kernel_launch(void* const* d_in, const int* in_sizes, int n_in,
                              void* d_out, int out_size, void* d_ws, size_t ws_size,
                              hipStream_t stream) {
    const float* keypoint = (const float*)d_in[0];  // B*3*M
    const float* pc       = (const float*)d_in[1];  // B*3*N
    const float* sn       = (const float*)d_in[2];  // B*3*N
    float* out            = (float*)d_out;          // B*M

    posloss_kernel<<<(PB * PM) / KPB, 256, 0, stream>>>(keypoint, pc, sn, out);
}